// Round 19
// baseline (77.780 us; speedup 1.0000x reference)
//
#include <hip/hip_runtime.h>

#define BB 512
#define TT 512
#define KK 128
#define CS 144    // chain stride in shorts: uniform 2-way banks (verified R18: 0 conflicts)
#define NSEG 16
#define SEGL 32
#define WARM 8    // contraction 0.151^8 ~ 3e-7: junction error negligible

typedef __attribute__((ext_vector_type(8))) short short8;   // 8 x bf16 bits
typedef __attribute__((ext_vector_type(4))) float f32x4;

__device__ __forceinline__ unsigned short f2bf(float f) {
  unsigned u = __float_as_uint(f);
  unsigned r = ((u >> 16) & 1u) + 0x7fffu;
  return (unsigned short)((u + r) >> 16);
}
__device__ __forceinline__ float bf2f(unsigned short h) {
  return __uint_as_float(((unsigned)h) << 16);
}

// K1: 512 blocks x 256 threads = 2048 INDEPENDENT single-wave chains.
// Wave (g, s): batch-quad g (batches 4g..4g+3), segment s of NSEG.
// FOUR chains packed in MFMA A-rows (A[row][k] = state[row&3][k], row=lane&15
// -- layout verified R13-R18). ONE wave does the full matvec: 8 col-tiles x
// 4 k-chunks = 32 MFMAs/step. D: row = 4*(lane>>4)+reg -> chain = reg;
// lane (lg,lc) finalizes chain lg, cols j = 16T+lc, T=0..7 (8 outputs/lane).
// NO barriers anywhere: LDS double-buffer is private to the wave; compiler
// inserts counted lgkmcnt for the intra-wave ds_write -> ds_read ordering.
// Segment s covers t in (32s, 32(s+1)]; s>0 starts WARM steps early from the
// all-ones state (Hilbert contraction; junction telescoped in K2 via exported
// (M, state[0]) at warmup-end "mid" and segment end -- scheme verified R18).
// Scaled bf16 state, lagged power-of-2 rescale; d_c = exponent of state[c][0]
// via readlane from A0 (lanes 0..3).
__global__ __launch_bounds__(256, 2) void crf_seg_kernel(
    const float* __restrict__ pot, const int* __restrict__ tags,
    const float* __restrict__ trans, unsigned short* __restrict__ wsv,
    float* __restrict__ wsm, float* __restrict__ wssc) {
  const float C = 1.4426950408889634f;    // 1/ln2
  const int tid = threadIdx.x;
  const int lane = tid & 63;
  const int wv = tid >> 6;
  const int bid = blockIdx.x;
  const int g = bid >> 2;                 // batch-quad 0..127
  const int s = ((bid & 3) << 2) | wv;    // segment 0..15
  const int lg = lane >> 4;               // lane group (epilogue chain)
  const int lc = lane & 15;
  const int crA = lc & 3;                 // A-row chain

  __shared__ alignas(16) unsigned short sb[4][2][4][CS];  // [wave][parity][chain][j]
  auto* sbw = sb[wv];

  // ---- sequence score: waves s<4 handle batch 4g+s ----
  if (s < 4) {
    int bb = 4 * g + s;
    int base = 8 * lane;
    const float* pbs = pot + (size_t)bb * TT * KK;
    int4 tgA = *(const int4*)&tags[bb * TT + base];
    int4 tgB = *(const int4*)&tags[bb * TT + base + 4];
    float sc =
        pbs[(size_t)(base + 0) * KK + tgA.x] + pbs[(size_t)(base + 1) * KK + tgA.y] +
        pbs[(size_t)(base + 2) * KK + tgA.z] + pbs[(size_t)(base + 3) * KK + tgA.w] +
        pbs[(size_t)(base + 4) * KK + tgB.x] + pbs[(size_t)(base + 5) * KK + tgB.y] +
        pbs[(size_t)(base + 6) * KK + tgB.z] + pbs[(size_t)(base + 7) * KK + tgB.w];
    sc += trans[tgA.x * KK + tgA.y] + trans[tgA.y * KK + tgA.z] +
          trans[tgA.z * KK + tgA.w] + trans[tgA.w * KK + tgB.x] +
          trans[tgB.x * KK + tgB.y] + trans[tgB.y * KK + tgB.z] +
          trans[tgB.z * KK + tgB.w];
    if (base + 8 < TT) sc += trans[tgB.w * KK + tags[bb * TT + base + 8]];
    #pragma unroll
    for (int off = 32; off; off >>= 1) sc += __shfl_xor(sc, off, 64);
    if (lane == 0) wssc[bb] = sc;
  }

  // ---- B fragments: 8 col-tiles x 4 k-chunks (forward E) ----
  short8 Bf[8][4];
  #pragma unroll
  for (int T = 0; T < 8; ++T) {
    const int j = 16 * T + lc;
    #pragma unroll
    for (int kc = 0; kc < 4; ++kc) {
      #pragma unroll
      for (int e = 0; e < 8; ++e) {
        Bf[T][kc][e] =
            (short)f2bf(__builtin_amdgcn_exp2f(trans[(32 * kc + 8 * lg + e) * KK + j] * C));
      }
    }
  }

  const int rstart = (s == 0) ? 1 : (SEGL * s - WARM + 1);
  const int nwarm = (s == 0) ? 0 : WARM;
  const int nmain = (s == NSEG - 1) ? (SEGL - 1) : SEGL;
  const int nsteps = nwarm + nmain;
  const float* ppc = pot + (size_t)(4 * g + lg) * TT * KK;  // chain lg's pot

  // ---- init state at parity 0 ----
  if (s == 0) {
    #pragma unroll
    for (int T = 0; T < 8; ++T)
      sbw[0][lg][16 * T + lc] = f2bf(__builtin_amdgcn_exp2f(ppc[16 * T + lc] * C));
  } else {
    #pragma unroll
    for (int T = 0; T < 8; ++T)
      sbw[0][lg][16 * T + lc] = 0x3F80;   // bf16 1.0
  }

  // ---- pot prefetch: pe = even-step rows, po = odd-step rows ----
  float pe[8], po[8];
  #pragma unroll
  for (int T = 0; T < 8; ++T) {
    pe[T] = ppc[(size_t)rstart * KK + 16 * T + lc];
    po[T] = ppc[(size_t)(rstart + 1) * KK + 16 * T + lc];
  }

  int Mi = 0, MiMid = 0;
  float v0last = 1.f, vMid = 1.f;
  const f32x4 kZero = {0.f, 0.f, 0.f, 0.f};

  auto step = [&](int it, float (&cur)[8]) {
    const int p = it & 1, wr = p ^ 1;
    const unsigned short* sp = &sbw[p][crA][0];
    short8 A0 = *(const short8*)(sp + 8 * lg);
    short8 A1 = *(const short8*)(sp + 32 + 8 * lg);
    short8 A2 = *(const short8*)(sp + 64 + 8 * lg);
    short8 A3 = *(const short8*)(sp + 96 + 8 * lg);
    int e0 = (int)(unsigned short)A0[0];
    int d0 = ((__builtin_amdgcn_readlane(e0, 0) >> 7) & 0xFF) - 127;
    int d1 = ((__builtin_amdgcn_readlane(e0, 1) >> 7) & 0xFF) - 127;
    int d2 = ((__builtin_amdgcn_readlane(e0, 2) >> 7) & 0xFF) - 127;
    int d3 = ((__builtin_amdgcn_readlane(e0, 3) >> 7) & 0xFF) - 127;
    int dc = (lg == 0) ? d0 : ((lg == 1) ? d1 : ((lg == 2) ? d2 : d3));
    float fd = (float)(-dc);
    int rn = rstart + it + 2;
    if (rn > TT - 1) rn = TT - 1;
    f32x4 a0, a1, a2, a3, a4, a5, a6, a7;
    a0 = __builtin_amdgcn_mfma_f32_16x16x32_bf16(A3, Bf[0][3], kZero, 0, 0, 0);
    a1 = __builtin_amdgcn_mfma_f32_16x16x32_bf16(A3, Bf[1][3], kZero, 0, 0, 0);
    a2 = __builtin_amdgcn_mfma_f32_16x16x32_bf16(A3, Bf[2][3], kZero, 0, 0, 0);
    a3 = __builtin_amdgcn_mfma_f32_16x16x32_bf16(A3, Bf[3][3], kZero, 0, 0, 0);
    a4 = __builtin_amdgcn_mfma_f32_16x16x32_bf16(A3, Bf[4][3], kZero, 0, 0, 0);
    a5 = __builtin_amdgcn_mfma_f32_16x16x32_bf16(A3, Bf[5][3], kZero, 0, 0, 0);
    a6 = __builtin_amdgcn_mfma_f32_16x16x32_bf16(A3, Bf[6][3], kZero, 0, 0, 0);
    a7 = __builtin_amdgcn_mfma_f32_16x16x32_bf16(A3, Bf[7][3], kZero, 0, 0, 0);
    a0 = __builtin_amdgcn_mfma_f32_16x16x32_bf16(A2, Bf[0][2], a0, 0, 0, 0);
    a1 = __builtin_amdgcn_mfma_f32_16x16x32_bf16(A2, Bf[1][2], a1, 0, 0, 0);
    a2 = __builtin_amdgcn_mfma_f32_16x16x32_bf16(A2, Bf[2][2], a2, 0, 0, 0);
    a3 = __builtin_amdgcn_mfma_f32_16x16x32_bf16(A2, Bf[3][2], a3, 0, 0, 0);
    a4 = __builtin_amdgcn_mfma_f32_16x16x32_bf16(A2, Bf[4][2], a4, 0, 0, 0);
    a5 = __builtin_amdgcn_mfma_f32_16x16x32_bf16(A2, Bf[5][2], a5, 0, 0, 0);
    a6 = __builtin_amdgcn_mfma_f32_16x16x32_bf16(A2, Bf[6][2], a6, 0, 0, 0);
    a7 = __builtin_amdgcn_mfma_f32_16x16x32_bf16(A2, Bf[7][2], a7, 0, 0, 0);
    a0 = __builtin_amdgcn_mfma_f32_16x16x32_bf16(A1, Bf[0][1], a0, 0, 0, 0);
    a1 = __builtin_amdgcn_mfma_f32_16x16x32_bf16(A1, Bf[1][1], a1, 0, 0, 0);
    a2 = __builtin_amdgcn_mfma_f32_16x16x32_bf16(A1, Bf[2][1], a2, 0, 0, 0);
    a3 = __builtin_amdgcn_mfma_f32_16x16x32_bf16(A1, Bf[3][1], a3, 0, 0, 0);
    a4 = __builtin_amdgcn_mfma_f32_16x16x32_bf16(A1, Bf[4][1], a4, 0, 0, 0);
    a5 = __builtin_amdgcn_mfma_f32_16x16x32_bf16(A1, Bf[5][1], a5, 0, 0, 0);
    a6 = __builtin_amdgcn_mfma_f32_16x16x32_bf16(A1, Bf[6][1], a6, 0, 0, 0);
    a7 = __builtin_amdgcn_mfma_f32_16x16x32_bf16(A1, Bf[7][1], a7, 0, 0, 0);
    a0 = __builtin_amdgcn_mfma_f32_16x16x32_bf16(A0, Bf[0][0], a0, 0, 0, 0);
    a1 = __builtin_amdgcn_mfma_f32_16x16x32_bf16(A0, Bf[1][0], a1, 0, 0, 0);
    a2 = __builtin_amdgcn_mfma_f32_16x16x32_bf16(A0, Bf[2][0], a2, 0, 0, 0);
    a3 = __builtin_amdgcn_mfma_f32_16x16x32_bf16(A0, Bf[3][0], a3, 0, 0, 0);
    a4 = __builtin_amdgcn_mfma_f32_16x16x32_bf16(A0, Bf[4][0], a4, 0, 0, 0);
    a5 = __builtin_amdgcn_mfma_f32_16x16x32_bf16(A0, Bf[5][0], a5, 0, 0, 0);
    a6 = __builtin_amdgcn_mfma_f32_16x16x32_bf16(A0, Bf[6][0], a6, 0, 0, 0);
    a7 = __builtin_amdgcn_mfma_f32_16x16x32_bf16(A0, Bf[7][0], a7, 0, 0, 0);
    // epilogue: lane takes chain lg (acc reg lg) of each tile
    #pragma unroll
    for (int T = 0; T < 8; ++T) {
      f32x4 aT = (T == 0) ? a0 : (T == 1) ? a1 : (T == 2) ? a2 : (T == 3) ? a3
               : (T == 4) ? a4 : (T == 5) ? a5 : (T == 6) ? a6 : a7;
      float z = (lg == 0) ? aT[0] : ((lg == 1) ? aT[1] : ((lg == 2) ? aT[2] : aT[3]));
      float u = cur[T];
      cur[T] = ppc[(size_t)rn * KK + 16 * T + lc];   // reload for step it+2
      float v = z * __builtin_amdgcn_exp2f(fmaf(u, C, fd));
      if (T == 0) v0last = v;
      sbw[wr][lg][16 * T + lc] = f2bf(v);
    }
    Mi += dc;
  };

  int it = 0;
  if (s > 0) {                            // warmup: 8 steps, capture "mid"
    #pragma unroll
    for (int q = 0; q < WARM / 2; ++q) {
      step(it, pe); ++it;
      step(it, po); ++it;
    }
    vMid = v0last; MiMid = Mi;
  }
  while (it + 1 < nsteps) {
    step(it, pe); ++it;
    step(it, po); ++it;
  }
  if (it < nsteps) { step(it, pe); ++it; }

  // ---- export junction scalars (lanes lc==0; chain = lg) ----
  if (lc == 0) {
    float* jp = &wsm[(((size_t)g * NSEG + s) * 4 + lg) * 4];
    jp[0] = (float)MiMid;   // M at warmup end
    jp[1] = vMid;           // state[0] at warmup end
    jp[2] = (float)Mi;      // M at segment end
    jp[3] = v0last;         // state[0] at segment end
  }
  // ---- last segment: export final state vectors ----
  if (s == NSEG - 1) {
    const int fin = nsteps & 1;           // 39 -> parity 1
    #pragma unroll
    for (int T = 0; T < 8; ++T)
      wsv[(size_t)(4 * g + lg) * KK + 16 * T + lc] = sbw[fin][lg][16 * T + lc];
  }
}

// K2: per batch: logZ2 = M_end(15) + log2(sum w15) + telescoped junctions.
__global__ __launch_bounds__(256) void crf_combine_kernel(
    const unsigned short* __restrict__ wsv, const float* __restrict__ wsm,
    const float* __restrict__ wssc, float* __restrict__ out) {
  const float LN2 = 0.6931471805599453f;
  const int tid = threadIdx.x;
  const int lane = tid & 63, wid = tid >> 6;
  const int b = blockIdx.x * 4 + wid;     // 128 blocks x 4 waves = 512
  const int g = b >> 2, c = b & 3;
  const unsigned short* vf = wsv + (size_t)b * KK;
  float sum = bf2f(vf[lane]) + bf2f(vf[lane + 64]);
  #pragma unroll
  for (int off = 32; off; off >>= 1) sum += __shfl_xor(sum, off, 64);
  if (lane == 0) {
    auto SC = [&](int s, int k) {
      return wsm[(((size_t)g * NSEG + s) * 4 + c) * 4 + k];
    };
    float l2 = SC(NSEG - 1, 2) + __builtin_amdgcn_logf(sum);  // v_log = log2
    #pragma unroll
    for (int s = 1; s < NSEG; ++s) {
      l2 += SC(s - 1, 2) + __builtin_amdgcn_logf(SC(s - 1, 3));
      l2 -= SC(s, 0) + __builtin_amdgcn_logf(SC(s, 1));
    }
    out[b] = wssc[b] - l2 * LN2;
  }
}

extern "C" void kernel_launch(void* const* d_in, const int* in_sizes, int n_in,
                              void* d_out, int out_size, void* d_ws, size_t ws_size,
                              hipStream_t stream) {
  const float* pot = (const float*)d_in[0];
  const int* tags = (const int*)d_in[1];
  const float* trans = (const float*)d_in[2];
  float* out = (float*)d_out;
  unsigned short* wsv = (unsigned short*)d_ws;                  // 512 x 128 bf16
  float* wsm = (float*)((char*)d_ws + (size_t)BB * KK * 2);     // 128x16x4 x 4 f32
  float* wssc = (float*)((char*)d_ws + (size_t)BB * KK * 2 +
                         (size_t)128 * NSEG * 4 * 4 * 4);       // 512 f32
  crf_seg_kernel<<<512, 256, 0, stream>>>(pot, tags, trans, wsv, wsm, wssc);
  crf_combine_kernel<<<BB / 4, 256, 0, stream>>>(wsv, wsm, wssc, out);
}